// Round 3
// baseline (10060.238 us; speedup 1.0000x reference)
//
#include <hip/hip_runtime.h>
#include <math.h>

#define GEPS 1e-7f
#define BNEPS 1e-5f

typedef unsigned short u16;
typedef unsigned int   u32;

// fp16 storage (RNE via hardware cvt), fp32 compute everywhere
__device__ __forceinline__ float h2f(u16 u){
  _Float16 x = __builtin_bit_cast(_Float16, u); return (float)x;
}
__device__ __forceinline__ u16 f2h(float f){
  _Float16 x = (_Float16)f; return __builtin_bit_cast(u16, x);
}

// ---------------------------------------------------------------- utilities
__global__ __launch_bounds__(256) void k_zero_i(int* __restrict__ p, int n){
  int i = blockIdx.x*256 + threadIdx.x;
  if (i < n) p[i] = 0;
}
__global__ __launch_bounds__(256) void k_zero_f(float* __restrict__ p, int n){
  int i = blockIdx.x*256 + threadIdx.x;
  if (i < n) p[i] = 0.f;
}

// ---------------------------------------------------------------- CSR build
__global__ __launch_bounds__(256) void k_hist(const int* __restrict__ dst, int E,
                                              int* __restrict__ cnt){
  int e = blockIdx.x*256 + threadIdx.x;
  if (e < E) atomicAdd(&cnt[dst[e]], 1);
}

__global__ __launch_bounds__(1024) void k_scan(int* __restrict__ cnt, int* __restrict__ offs,
                                               int N, int E){
  __shared__ int lsum[1024];
  int t = threadIdx.x;
  int C = (N + 1023) >> 10;
  int st = t*C, en = min(st + C, N);
  int sum = 0;
  for (int i = st; i < en; ++i) sum += cnt[i];
  lsum[t] = sum;
  __syncthreads();
  for (int off = 1; off < 1024; off <<= 1){
    int v = (t >= off) ? lsum[t-off] : 0;
    __syncthreads();
    lsum[t] += v;
    __syncthreads();
  }
  int run = lsum[t] - sum;  // exclusive prefix
  for (int i = st; i < en; ++i){
    int c = cnt[i];
    offs[i] = run;
    cnt[i]  = run;          // becomes scatter cursor
    run += c;
  }
  if (t == 1023) offs[N] = E;
}

__global__ __launch_bounds__(256) void k_scatter(const int* __restrict__ src,
    const int* __restrict__ dst, const int* __restrict__ attr, int E,
    int* __restrict__ cursor, int* __restrict__ esort){
  int e = blockIdx.x*256 + threadIdx.x;
  if (e >= E) return;
  int d = dst[e];
  int pos = atomicAdd(&cursor[d], 1);
  int a = (src[e] & 0x1ffff)
        | ((attr[3*(size_t)e]   & 15) << 17)
        | ((attr[3*(size_t)e+1] & 15) << 21)
        | ((attr[3*(size_t)e+2] & 15) << 25);
  esort[pos] = a;
}

// ---------------------------------------------------------------- atom encoder
// writes h (fp32 residual stream) and h2 (fp16 copy, input to layer-0 edge pass)
__global__ __launch_bounds__(256) void k_atom(const int* __restrict__ x,
    const float* __restrict__ emb, float* __restrict__ h, u16* __restrict__ h2, int N){
  int d = threadIdx.x & 127;
  int n = (blockIdx.x << 1) + (threadIdx.x >> 7);
  if (n >= N) return;
  float s = 0.f;
  #pragma unroll
  for (int i = 0; i < 9; ++i){
    int idx = x[(size_t)n*9 + i];
    s += emb[((size_t)i*119 + idx)*128 + d];
  }
  h[(size_t)n*128 + d]  = s;
  h2[(size_t)n*128 + d] = f2h(s);
}

// ---------------------------------------------------------------- pre-norm relu(bn(h)) -> fp16
__global__ __launch_bounds__(256) void k_prenorm(const float* __restrict__ h,
    u16* __restrict__ h2, const float* __restrict__ ssum, const float* __restrict__ ssq,
    const float* __restrict__ g, const float* __restrict__ b, int N){
  int i = blockIdx.x*256 + threadIdx.x;
  if (i >= N*128) return;
  int d = i & 127;
  float inv = 1.f / (float)N;
  float mu  = ssum[d] * inv;
  float var = fmaxf(ssq[d]*inv - mu*mu, 0.f);
  float rs  = rsqrtf(var + BNEPS);
  float sg  = g[d] * rs;
  h2[i] = f2h(fmaxf((h[i] - mu)*sg + b[d], 0.f));
}

// ---------------------------------------------------------------- fused edge pass:
// per node: online softmax over incident edges, writes hh = hsrc + aggregated msg (fp16)
__global__ __launch_bounds__(256) void k_edge(const u16* __restrict__ hsrc,
    const int* __restrict__ offs, const int* __restrict__ esort,
    const float* __restrict__ bond,   // [3,6,128] for this layer
    const float* __restrict__ tptr,   // &t[l]
    u16* __restrict__ hh, int N){
  int d = threadIdx.x & 127;
  int n = (blockIdx.x << 1) + (threadIdx.x >> 7);
  if (n >= N) return;
  float tl = *tptr;
  int s0 = offs[n], s1 = offs[n+1];
  float mmax = -__builtin_inff(), ssum = 0.f, acc = 0.f;
  for (int e = s0; e < s1; ++e){
    int se = esort[e];
    int sidx = se & 0x1ffff;
    int a0 = (se >> 17) & 15, a1 = (se >> 21) & 15, a2 = (se >> 25) & 15;
    float ev  = bond[a0*128 + d] + bond[(6 + a1)*128 + d] + bond[(12 + a2)*128 + d];
    float msg = fmaxf(h2f(hsrc[(size_t)sidx*128 + d]) + ev, 0.f) + GEPS;
    float v = msg * tl;
    float mnew = fmaxf(mmax, v);
    float corr = __expf(mmax - mnew);   // exp(-inf)=0 on first edge
    float p    = __expf(v - mnew);
    ssum = ssum*corr + p;
    acc  = acc*corr + p*msg;
    mmax = mnew;
  }
  float m = acc / fmaxf(ssum, GEPS);    // empty segment -> 0 (matches isfinite guard)
  hh[(size_t)n*128 + d] = f2h(h2f(hsrc[(size_t)n*128 + d]) + m);
}

// ---------------------------------------------------------------- SGEMM 128x128 tile,
// 8x8 per thread. A is fp16 (fp32 compute). Optional fused BN+relu on A-load, optional
// fp32 residual, output fp16 or fp32. Stats (sum/sumsq per column) are accumulated from
// the ROUNDED stored values so the downstream BN is exactly consistent with its input.
template<bool PRE_BN, bool OUT_LP>
__global__ __launch_bounds__(256)
void k_gemm(const u16* __restrict__ A, int lda,
            const float* __restrict__ B, int ldb,
            const float* __restrict__ bias,
            const float* __restrict__ sIn, const float* __restrict__ qIn,
            const float* __restrict__ gam, const float* __restrict__ bet,
            const float* __restrict__ resid,
            void* __restrict__ outv, int ldo,
            float* __restrict__ sOut, float* __restrict__ qOut,
            int M, int K){
  __shared__ float As[16][132];   // transposed A tile, +4 pad keeps b128 alignment
  __shared__ float Bs[16][128];
  __shared__ float red[16][128];
  __shared__ float sc[256], shv[256];

  int tid = threadIdx.x;
  if (PRE_BN){
    float inv = 1.f / (float)M;
    for (int k = tid; k < K; k += 256){
      float mu  = sIn[k]*inv;
      float var = fmaxf(qIn[k]*inv - mu*mu, 0.f);
      float rs  = rsqrtf(var + BNEPS);
      float s   = gam[k]*rs;
      sc[k]  = s;
      shv[k] = bet[k] - mu*s;
    }
    __syncthreads();
  }
  int mBase = blockIdx.x * 128;
  int cBase = blockIdx.y * 128;
  int tx = tid & 15, ty = tid >> 4;

  int arow = tid >> 1;
  int akb  = (tid & 1) * 8;
  int brow = tid >> 4;
  int bcol = (tid & 15) * 8;

  float acc[8][8];
  #pragma unroll
  for (int i = 0; i < 8; ++i)
    #pragma unroll
    for (int j = 0; j < 8; ++j) acc[i][j] = 0.f;

  for (int k0 = 0; k0 < K; k0 += 16){
    int gr = mBase + arow; if (gr >= M) gr = M - 1;   // clamp; garbage rows discarded later
    const u16* ap = A + (size_t)gr*lda + (k0 + akb);
    uint4 raw = *(const uint4*)ap;                     // 8 fp16, 16B aligned
    float av[8];
    av[0]=h2f((u16)(raw.x & 0xffff)); av[1]=h2f((u16)(raw.x >> 16));
    av[2]=h2f((u16)(raw.y & 0xffff)); av[3]=h2f((u16)(raw.y >> 16));
    av[4]=h2f((u16)(raw.z & 0xffff)); av[5]=h2f((u16)(raw.z >> 16));
    av[6]=h2f((u16)(raw.w & 0xffff)); av[7]=h2f((u16)(raw.w >> 16));
    if (PRE_BN){
      int kb = k0 + akb;
      #pragma unroll
      for (int j = 0; j < 8; ++j) av[j] = fmaxf(av[j]*sc[kb+j] + shv[kb+j], 0.f);
    }
    #pragma unroll
    for (int j = 0; j < 8; ++j) As[akb+j][arow] = av[j];

    const float* bp = B + (size_t)(k0 + brow)*ldb + cBase + bcol;
    *(float4*)&Bs[brow][bcol]     = *(const float4*)(bp);
    *(float4*)&Bs[brow][bcol + 4] = *(const float4*)(bp + 4);
    __syncthreads();

    #pragma unroll
    for (int kk = 0; kk < 16; ++kk){
      float4 a0 = *(const float4*)&As[kk][ty*4];
      float4 a1 = *(const float4*)&As[kk][64 + ty*4];
      float4 b0 = *(const float4*)&Bs[kk][tx*4];
      float4 b1 = *(const float4*)&Bs[kk][64 + tx*4];
      float a8[8] = {a0.x,a0.y,a0.z,a0.w,a1.x,a1.y,a1.z,a1.w};
      float b8[8] = {b0.x,b0.y,b0.z,b0.w,b1.x,b1.y,b1.z,b1.w};
      #pragma unroll
      for (int i = 0; i < 8; ++i)
        #pragma unroll
        for (int j = 0; j < 8; ++j)
          acc[i][j] += a8[i]*b8[j];
    }
    __syncthreads();
  }

  float4 bLo = *(const float4*)&bias[cBase + tx*4];
  float4 bHi = *(const float4*)&bias[cBase + 64 + tx*4];
  float bb[8] = {bLo.x,bLo.y,bLo.z,bLo.w,bHi.x,bHi.y,bHi.z,bHi.w};
  float cs[8], cq[8];
  #pragma unroll
  for (int j = 0; j < 8; ++j){ cs[j] = 0.f; cq[j] = 0.f; }

  #pragma unroll
  for (int i = 0; i < 8; ++i){
    int r = mBase + ((i < 4) ? (ty*4 + i) : (64 + ty*4 + i - 4));
    if (r < M){
      float v[8];
      #pragma unroll
      for (int j = 0; j < 8; ++j) v[j] = acc[i][j] + bb[j];
      size_t rowoff = (size_t)r*ldo + cBase;
      if (!OUT_LP){
        float* out = (float*)outv;
        if (resid){
          float4 r0 = *(const float4*)&resid[rowoff + tx*4];
          float4 r1 = *(const float4*)&resid[rowoff + 64 + tx*4];
          v[0]+=r0.x; v[1]+=r0.y; v[2]+=r0.z; v[3]+=r0.w;
          v[4]+=r1.x; v[5]+=r1.y; v[6]+=r1.z; v[7]+=r1.w;
        }
        float4 o0 = {v[0],v[1],v[2],v[3]};
        float4 o1 = {v[4],v[5],v[6],v[7]};
        *(float4*)&out[rowoff + tx*4]      = o0;
        *(float4*)&out[rowoff + 64 + tx*4] = o1;
        #pragma unroll
        for (int j = 0; j < 8; ++j){ cs[j] += v[j]; cq[j] += v[j]*v[j]; }
      } else {
        u16* out = (u16*)outv;
        ushort4 o0, o1;
        o0.x=f2h(v[0]); o0.y=f2h(v[1]); o0.z=f2h(v[2]); o0.w=f2h(v[3]);
        o1.x=f2h(v[4]); o1.y=f2h(v[5]); o1.z=f2h(v[6]); o1.w=f2h(v[7]);
        *(ushort4*)&out[rowoff + tx*4]      = o0;
        *(ushort4*)&out[rowoff + 64 + tx*4] = o1;
        // stats from the ROUNDED values -> downstream BN sees consistent data
        float vr[8] = {h2f(o0.x),h2f(o0.y),h2f(o0.z),h2f(o0.w),
                       h2f(o1.x),h2f(o1.y),h2f(o1.z),h2f(o1.w)};
        #pragma unroll
        for (int j = 0; j < 8; ++j){ cs[j] += vr[j]; cq[j] += vr[j]*vr[j]; }
      }
    }
  }
  // per-column stats: block reduce in LDS, one atomic per column per block
  #pragma unroll
  for (int j = 0; j < 4; ++j){ red[ty][tx*4+j] = cs[j]; red[ty][64+tx*4+j] = cs[4+j]; }
  __syncthreads();
  if (tid < 128){
    float s = 0.f;
    #pragma unroll
    for (int rI = 0; rI < 16; ++rI) s += red[rI][tid];
    atomicAdd(&sOut[cBase + tid], s);
  }
  __syncthreads();
  #pragma unroll
  for (int j = 0; j < 4; ++j){ red[ty][tx*4+j] = cq[j]; red[ty][64+tx*4+j] = cq[4+j]; }
  __syncthreads();
  if (tid < 128){
    float s = 0.f;
    #pragma unroll
    for (int rI = 0; rI < 16; ++rI) s += red[rI][tid];
    atomicAdd(&qOut[cBase + tid], s);
  }
}

// ---------------------------------------------------------------- pooling: final bn fused,
// per-node dot with predW, atomic segment-sum per graph
__global__ __launch_bounds__(256) void k_pool(const float* __restrict__ h,
    const float* __restrict__ ssum, const float* __restrict__ ssq,
    const float* __restrict__ g, const float* __restrict__ b,
    const float* __restrict__ predW, const int* __restrict__ batch,
    float* __restrict__ pool, float* __restrict__ cnt, int N){
  int lane = threadIdx.x & 63;
  int n = (blockIdx.x << 2) + (threadIdx.x >> 6);
  if (n >= N) return;
  float inv = 1.f / (float)N;
  float v = 0.f;
  #pragma unroll
  for (int d = lane; d < 128; d += 64){
    float mu  = ssum[d]*inv;
    float var = fmaxf(ssq[d]*inv - mu*mu, 0.f);
    float rs  = rsqrtf(var + BNEPS);
    float bn  = (h[(size_t)n*128 + d] - mu)*(g[d]*rs) + b[d];
    v += bn * predW[d];
  }
  #pragma unroll
  for (int off = 32; off > 0; off >>= 1) v += __shfl_down(v, off, 64);
  if (lane == 0){
    int gi = batch[n];
    atomicAdd(&pool[gi], v);
    atomicAdd(&cnt[gi], 1.f);
  }
}

__global__ __launch_bounds__(256) void k_final(const float* __restrict__ pool,
    const float* __restrict__ cnt, const float* __restrict__ predb,
    float* __restrict__ out, int G){
  int g = blockIdx.x*256 + threadIdx.x;
  if (g < G) out[g] = pool[g] / fmaxf(cnt[g], 1.f) + predb[0];
}

// ---------------------------------------------------------------- launcher
extern "C" void kernel_launch(void* const* d_in, const int* in_sizes, int n_in,
                              void* d_out, int out_size, void* d_ws, size_t ws_size,
                              hipStream_t stream){
  const int*   x        = (const int*)d_in[0];
  const int*   eidx     = (const int*)d_in[1];
  const int*   eattr    = (const int*)d_in[2];
  const int*   batch    = (const int*)d_in[3];
  const float* atom_emb = (const float*)d_in[4];
  const float* bond_emb = (const float*)d_in[5];
  const float* W1 = (const float*)d_in[6];
  const float* b1 = (const float*)d_in[7];
  const float* g1 = (const float*)d_in[8];
  const float* be1= (const float*)d_in[9];
  const float* W2 = (const float*)d_in[10];
  const float* b2 = (const float*)d_in[11];
  const float* g2 = (const float*)d_in[12];
  const float* be2= (const float*)d_in[13];
  const float* W3 = (const float*)d_in[14];
  const float* b3 = (const float*)d_in[15];
  const float* tt = (const float*)d_in[16];
  const float* ng = (const float*)d_in[17];
  const float* nb = (const float*)d_in[18];
  const float* predW = (const float*)d_in[19];
  const float* predb = (const float*)d_in[20];
  float* out = (float*)d_out;

  const int N = in_sizes[3];
  const int E = in_sizes[1] / 2;
  const int L = in_sizes[16];
  const int G = out_size;
  const int D = 128, H = 256;

  char* ws = (char*)d_ws;
  size_t off = 0;
  auto carve = [&](size_t bytes)->void*{
    void* p = ws + off;
    off += (bytes + 511) & ~(size_t)511;
    return p;
  };
  // total ~182 MB
  float* h   = (float*)carve((size_t)N*D*4);   // fp32 residual stream
  u16*   h2  = (u16*)  carve((size_t)N*D*2);   // fp16 relu(bn(h))
  u16*   y1  = (u16*)  carve((size_t)N*H*2);   // fp16
  u16*   y2  = (u16*)  carve((size_t)N*H*2);   // fp16
  u16*   hh  = y2;   // hh (fp16, N*D) lives in y2's space; dead before GEMM2 writes y2
  int*  offs   = (int*)carve((size_t)(N+1)*4);
  int*  cursor = (int*)carve((size_t)N*4);
  int*  esort  = (int*)carve((size_t)E*4);
  float* stats = (float*)carve(1280*4);
  float* s1s = stats,        *s1q = stats + 256;
  float* s2s = stats + 512,  *s2q = stats + 768;
  float* shs = stats + 1024, *shq = stats + 1152;
  float* pool = (float*)carve((size_t)G*4);
  float* cnt  = (float*)carve((size_t)G*4);

  // CSR build (once per call, shared by all 20 layers)
  k_zero_i <<<(N+255)/256, 256, 0, stream>>>(cursor, N);
  k_hist   <<<(E+255)/256, 256, 0, stream>>>(eidx + E, E, cursor);
  k_scan   <<<1, 1024, 0, stream>>>(cursor, offs, N, E);
  k_scatter<<<(E+255)/256, 256, 0, stream>>>(eidx, eidx + E, eattr, E, cursor, esort);
  k_atom   <<<(N+1)/2, 256, 0, stream>>>(x, atom_emb, h, h2, N);

  int mb = (N + 127) / 128;
  for (int l = 0; l < L; ++l){
    if (l > 0){
      k_prenorm<<<(N*D+255)/256, 256, 0, stream>>>(h, h2, shs, shq,
          ng + (size_t)(l-1)*D, nb + (size_t)(l-1)*D, N);
    }
    k_zero_f<<<(1280+255)/256, 256, 0, stream>>>(stats, 1280);
    k_edge  <<<(N+1)/2, 256, 0, stream>>>(h2, offs, esort,
        bond_emb + (size_t)l*3*6*D, tt + l, hh, N);
    // y1 = hh @ W1 + b1   (stats -> s1)
    k_gemm<false,true><<<dim3(mb,2), 256, 0, stream>>>(hh, D, W1 + (size_t)l*D*H, H,
        b1 + (size_t)l*H, nullptr, nullptr, nullptr, nullptr, nullptr,
        y1, H, s1s, s1q, N, D);
    // y2 = relu(bn(y1)) @ W2 + b2   (stats -> s2)
    k_gemm<true,true><<<dim3(mb,2), 256, 0, stream>>>(y1, H, W2 + (size_t)l*H*H, H,
        b2 + (size_t)l*H, s1s, s1q, g1 + (size_t)l*H, be1 + (size_t)l*H, nullptr,
        y2, H, s2s, s2q, N, H);
    // h = relu(bn(y2)) @ W3 + b3 (+ h residual for l>0)   (stats of new h -> sh)
    k_gemm<true,false><<<dim3(mb,1), 256, 0, stream>>>(y2, H, W3 + (size_t)l*H*D, D,
        b3 + (size_t)l*D, s2s, s2q, g2 + (size_t)l*H, be2 + (size_t)l*H,
        (l ? h : nullptr), h, D, shs, shq, N, H);
  }

  k_zero_f<<<(G+255)/256, 256, 0, stream>>>(pool, G);
  k_zero_f<<<(G+255)/256, 256, 0, stream>>>(cnt,  G);
  k_pool  <<<(N+3)/4, 256, 0, stream>>>(h, shs, shq,
      ng + (size_t)(L-1)*D, nb + (size_t)(L-1)*D, predW, batch, pool, cnt, N);
  k_final <<<(G+255)/256, 256, 0, stream>>>(pool, cnt, predb, out, G);
}

// Round 4
// 7093.771 us; speedup vs baseline: 1.4182x; 1.4182x over previous
//
#include <hip/hip_runtime.h>
#include <math.h>

#define GEPS 1e-7f
#define BNEPS 1e-5f

typedef unsigned short u16;
typedef unsigned int   u32;

typedef _Float16 f16x8 __attribute__((ext_vector_type(8)));
typedef float    f32x4 __attribute__((ext_vector_type(4)));

__device__ __forceinline__ float h2f(u16 u){
  _Float16 x = __builtin_bit_cast(_Float16, u); return (float)x;
}
__device__ __forceinline__ u16 f2h(float f){
  _Float16 x = (_Float16)f; return __builtin_bit_cast(u16, x);
}

// ---------------------------------------------------------------- utilities
__global__ __launch_bounds__(256) void k_zero_i(int* __restrict__ p, int n){
  int i = blockIdx.x*256 + threadIdx.x;
  if (i < n) p[i] = 0;
}
__global__ __launch_bounds__(256) void k_zero_f(float* __restrict__ p, int n){
  int i = blockIdx.x*256 + threadIdx.x;
  if (i < n) p[i] = 0.f;
}

// ---------------------------------------------------------------- CSR build (multi-block scan)
__global__ __launch_bounds__(256) void k_hist(const int* __restrict__ dst, int E,
                                              int* __restrict__ cnt){
  int e = blockIdx.x*256 + threadIdx.x;
  if (e < E) atomicAdd(&cnt[dst[e]], 1);
}

__global__ __launch_bounds__(256) void k_blocksum(const int* __restrict__ cnt, int N,
                                                  int* __restrict__ part){
  __shared__ int s[256];
  int t = threadIdx.x, i = blockIdx.x*256 + t;
  s[t] = (i < N) ? cnt[i] : 0;
  __syncthreads();
  for (int off = 128; off > 0; off >>= 1){
    if (t < off) s[t] += s[t + off];
    __syncthreads();
  }
  if (t == 0) part[blockIdx.x] = s[0];
}

__global__ __launch_bounds__(1024) void k_scanpart(int* __restrict__ part, int NB){
  __shared__ int s[1024];
  int t = threadIdx.x;
  int v = (t < NB) ? part[t] : 0;
  s[t] = v;
  __syncthreads();
  for (int off = 1; off < 1024; off <<= 1){
    int u = (t >= off) ? s[t-off] : 0;
    __syncthreads();
    s[t] += u;
    __syncthreads();
  }
  if (t < NB) part[t] = s[t] - v;   // exclusive
}

__global__ __launch_bounds__(256) void k_scanapply(const int* __restrict__ cnt,
    const int* __restrict__ part, int N, int E,
    int* __restrict__ offs, int* __restrict__ cursor){
  __shared__ int s[256];
  int t = threadIdx.x, i = blockIdx.x*256 + t;
  int v = (i < N) ? cnt[i] : 0;
  s[t] = v;
  __syncthreads();
  for (int off = 1; off < 256; off <<= 1){
    int u = (t >= off) ? s[t-off] : 0;
    __syncthreads();
    s[t] += u;
    __syncthreads();
  }
  int ex = part[blockIdx.x] + s[t] - v;
  if (i < N){
    offs[i]   = ex;
    cursor[i] = ex;
    if (i == N-1) offs[N] = ex + v;
  }
}

__global__ __launch_bounds__(256) void k_scatter(const int* __restrict__ src,
    const int* __restrict__ dst, const int* __restrict__ attr, int E,
    int* __restrict__ cursor, int* __restrict__ esort){
  int e = blockIdx.x*256 + threadIdx.x;
  if (e >= E) return;
  int d = dst[e];
  int pos = atomicAdd(&cursor[d], 1);
  int a = (src[e] & 0x1ffff)
        | ((attr[3*(size_t)e]   & 15) << 17)
        | ((attr[3*(size_t)e+1] & 15) << 21)
        | ((attr[3*(size_t)e+2] & 15) << 25);
  esort[pos] = a;
}

// ---------------------------------------------------------------- weight prep: fp32 [L][K][N] -> fp16 [L][N][K]
__global__ __launch_bounds__(256) void k_wtrans(const float* __restrict__ W,
    u16* __restrict__ Wt, int K, int Nout, int total){
  int id = blockIdx.x*256 + threadIdx.x;
  if (id >= total) return;
  int k   = id % K;
  int rem = id / K;
  int n   = rem % Nout;
  int l   = rem / Nout;
  Wt[id] = f2h(W[((size_t)l*K + k)*Nout + n]);
}

// ---------------------------------------------------------------- atom encoder
__global__ __launch_bounds__(256) void k_atom(const int* __restrict__ x,
    const float* __restrict__ emb, float* __restrict__ h, u16* __restrict__ h2, int N){
  int d = threadIdx.x & 127;
  int n = (blockIdx.x << 1) + (threadIdx.x >> 7);
  if (n >= N) return;
  float s = 0.f;
  #pragma unroll
  for (int i = 0; i < 9; ++i){
    int idx = x[(size_t)n*9 + i];
    s += emb[((size_t)i*119 + idx)*128 + d];
  }
  h[(size_t)n*128 + d]  = s;
  h2[(size_t)n*128 + d] = f2h(s);
}

// ---------------------------------------------------------------- pre-norm relu(bn(h)) -> fp16
__global__ __launch_bounds__(256) void k_prenorm(const float* __restrict__ h,
    u16* __restrict__ h2, const float* __restrict__ ssum, const float* __restrict__ ssq,
    const float* __restrict__ g, const float* __restrict__ b, int N){
  int i = blockIdx.x*256 + threadIdx.x;
  if (i >= N*128) return;
  int d = i & 127;
  float inv = 1.f / (float)N;
  float mu  = ssum[d] * inv;
  float var = fmaxf(ssq[d]*inv - mu*mu, 0.f);
  float rs  = rsqrtf(var + BNEPS);
  float sg  = g[d] * rs;
  h2[i] = f2h(fmaxf((h[i] - mu)*sg + b[d], 0.f));
}

// ---------------------------------------------------------------- fused edge pass (online softmax)
__global__ __launch_bounds__(256) void k_edge(const u16* __restrict__ hsrc,
    const int* __restrict__ offs, const int* __restrict__ esort,
    const float* __restrict__ bond, const float* __restrict__ tptr,
    u16* __restrict__ hh, int N){
  int d = threadIdx.x & 127;
  int n = (blockIdx.x << 1) + (threadIdx.x >> 7);
  if (n >= N) return;
  float tl = *tptr;
  int s0 = offs[n], s1 = offs[n+1];
  float mmax = -__builtin_inff(), ssum = 0.f, acc = 0.f;
  for (int e = s0; e < s1; ++e){
    int se = esort[e];
    int sidx = se & 0x1ffff;
    int a0 = (se >> 17) & 15, a1 = (se >> 21) & 15, a2 = (se >> 25) & 15;
    float ev  = bond[a0*128 + d] + bond[(6 + a1)*128 + d] + bond[(12 + a2)*128 + d];
    float msg = fmaxf(h2f(hsrc[(size_t)sidx*128 + d]) + ev, 0.f) + GEPS;
    float v = msg * tl;
    float mnew = fmaxf(mmax, v);
    float corr = __expf(mmax - mnew);
    float p    = __expf(v - mnew);
    ssum = ssum*corr + p;
    acc  = acc*corr + p*msg;
    mmax = mnew;
  }
  float m = acc / fmaxf(ssum, GEPS);
  hh[(size_t)n*128 + d] = f2h(h2f(hsrc[(size_t)n*128 + d]) + m);
}

// ---------------------------------------------------------------- MFMA fp16 GEMM, 128x128 tile
// C[M][Ncols] = op(A)[M][K] @ Wt^T (Wt is [Ncols][K] fp16) + bias.
// op(A): optional BN+relu from batch stats (A fp16, stats of rounded stored values).
// Output fp16 (stats from rounded) or fp32 with optional residual (stats from stored fp32).
// Per-column sum/sumsq accumulated for the downstream BN.
template<bool TRANSFORM, bool OUT32>
__global__ __launch_bounds__(256)
void k_gemm(const u16* __restrict__ A, int lda,
            const u16* __restrict__ Wt,
            const float* __restrict__ bias,
            const float* __restrict__ sIn, const float* __restrict__ qIn,
            const float* __restrict__ gam, const float* __restrict__ bet,
            const float* __restrict__ resid,
            void* __restrict__ outv, int ldo,
            float* __restrict__ sOut, float* __restrict__ qOut,
            int M, int K){
  __shared__ __align__(16) _Float16 As[128][40];   // pitch 40 f16 = 80B; banks covered, 2-way free
  __shared__ __align__(16) _Float16 Bs[128][40];
  __shared__ float sc[256], shv[256];
  __shared__ float sumc[128], sqc[128];

  int tid = threadIdx.x;
  if (TRANSFORM){
    float inv = 1.f / (float)M;
    for (int k = tid; k < K; k += 256){
      float mu  = sIn[k]*inv;
      float var = fmaxf(qIn[k]*inv - mu*mu, 0.f);
      float rs  = rsqrtf(var + BNEPS);
      float s   = gam[k]*rs;
      sc[k]  = s;
      shv[k] = bet[k] - mu*s;
    }
    __syncthreads();
  }

  int mBase = blockIdx.x * 128;
  int cBase = blockIdx.y * 128;
  int w    = tid >> 6;
  int lane = tid & 63;
  int wm = w & 1, wn = w >> 1;
  int quad = lane >> 4, ln = lane & 15;

  f32x4 acc[4][4];
  #pragma unroll
  for (int i = 0; i < 4; ++i)
    #pragma unroll
    for (int j = 0; j < 4; ++j)
      acc[i][j] = (f32x4){0.f,0.f,0.f,0.f};

  int kTiles = K >> 5;
  for (int kt = 0; kt < kTiles; ++kt){
    int k0 = kt << 5;
    // stage A (128 x 32) and Wt (128 x 32), 512 16B-segments each, 256 threads x2
    #pragma unroll
    for (int s = 0; s < 2; ++s){
      int idx = s*256 + tid;
      int row = idx >> 2;
      int seg = (idx & 3) << 3;           // k offset in halves
      int gr = mBase + row; if (gr >= M) gr = M - 1;
      uint4 ra = *(const uint4*)(A + (size_t)gr*lda + k0 + seg);
      if (TRANSFORM){
        int kb = k0 + seg;
        float f0 = fmaxf(h2f((u16)(ra.x & 0xffff))*sc[kb+0] + shv[kb+0], 0.f);
        float f1 = fmaxf(h2f((u16)(ra.x >> 16)) *sc[kb+1] + shv[kb+1], 0.f);
        float f2 = fmaxf(h2f((u16)(ra.y & 0xffff))*sc[kb+2] + shv[kb+2], 0.f);
        float f3 = fmaxf(h2f((u16)(ra.y >> 16)) *sc[kb+3] + shv[kb+3], 0.f);
        float f4 = fmaxf(h2f((u16)(ra.z & 0xffff))*sc[kb+4] + shv[kb+4], 0.f);
        float f5 = fmaxf(h2f((u16)(ra.z >> 16)) *sc[kb+5] + shv[kb+5], 0.f);
        float f6 = fmaxf(h2f((u16)(ra.w & 0xffff))*sc[kb+6] + shv[kb+6], 0.f);
        float f7 = fmaxf(h2f((u16)(ra.w >> 16)) *sc[kb+7] + shv[kb+7], 0.f);
        ra.x = (u32)f2h(f0) | ((u32)f2h(f1) << 16);
        ra.y = (u32)f2h(f2) | ((u32)f2h(f3) << 16);
        ra.z = (u32)f2h(f4) | ((u32)f2h(f5) << 16);
        ra.w = (u32)f2h(f6) | ((u32)f2h(f7) << 16);
      }
      *(uint4*)(&As[row][seg]) = ra;
      uint4 rb = *(const uint4*)(Wt + (size_t)(cBase + row)*K + k0 + seg);
      *(uint4*)(&Bs[row][seg]) = rb;
    }
    __syncthreads();

    f16x8 af[4], bf[4];
    #pragma unroll
    for (int i = 0; i < 4; ++i)
      af[i] = *(const f16x8*)(&As[64*wm + 16*i + ln][quad*8]);
    #pragma unroll
    for (int j = 0; j < 4; ++j)
      bf[j] = *(const f16x8*)(&Bs[64*wn + 16*j + ln][quad*8]);
    #pragma unroll
    for (int i = 0; i < 4; ++i)
      #pragma unroll
      for (int j = 0; j < 4; ++j)
        acc[i][j] = __builtin_amdgcn_mfma_f32_16x16x32_f16(af[i], bf[j], acc[i][j], 0, 0, 0);
    __syncthreads();
  }

  // epilogue
  float bv[4];
  #pragma unroll
  for (int j = 0; j < 4; ++j) bv[j] = bias[cBase + 64*wn + 16*j + ln];
  float ps[4] = {0,0,0,0}, pq[4] = {0,0,0,0};

  #pragma unroll
  for (int i = 0; i < 4; ++i){
    int rbase = mBase + 64*wm + 16*i + quad*4;
    #pragma unroll
    for (int r = 0; r < 4; ++r){
      int row = rbase + r;
      if (row < M){
        #pragma unroll
        for (int j = 0; j < 4; ++j){
          int col = cBase + 64*wn + 16*j + ln;
          size_t off = (size_t)row*ldo + col;
          float v = acc[i][j][r] + bv[j];
          if (OUT32){
            float* out = (float*)outv;
            if (resid) v += resid[off];
            out[off] = v;
            ps[j] += v; pq[j] += v*v;
          } else {
            u16* out = (u16*)outv;
            u16 q = f2h(v);
            out[off] = q;
            float vr = h2f(q);
            ps[j] += vr; pq[j] += vr*vr;
          }
        }
      }
    }
  }
  __syncthreads();
  if (tid < 128){ sumc[tid] = 0.f; sqc[tid] = 0.f; }
  __syncthreads();
  #pragma unroll
  for (int j = 0; j < 4; ++j){
    int cl = 64*wn + 16*j + ln;
    atomicAdd(&sumc[cl], ps[j]);
    atomicAdd(&sqc[cl],  pq[j]);
  }
  __syncthreads();
  if (tid < 128){
    atomicAdd(&sOut[cBase + tid], sumc[tid]);
    atomicAdd(&qOut[cBase + tid], sqc[tid]);
  }
}

// ---------------------------------------------------------------- pooling
__global__ __launch_bounds__(256) void k_pool(const float* __restrict__ h,
    const float* __restrict__ ssum, const float* __restrict__ ssq,
    const float* __restrict__ g, const float* __restrict__ b,
    const float* __restrict__ predW, const int* __restrict__ batch,
    float* __restrict__ pool, float* __restrict__ cnt, int N){
  int lane = threadIdx.x & 63;
  int n = (blockIdx.x << 2) + (threadIdx.x >> 6);
  if (n >= N) return;
  float inv = 1.f / (float)N;
  float v = 0.f;
  #pragma unroll
  for (int d = lane; d < 128; d += 64){
    float mu  = ssum[d]*inv;
    float var = fmaxf(ssq[d]*inv - mu*mu, 0.f);
    float rs  = rsqrtf(var + BNEPS);
    float bn  = (h[(size_t)n*128 + d] - mu)*(g[d]*rs) + b[d];
    v += bn * predW[d];
  }
  #pragma unroll
  for (int off = 32; off > 0; off >>= 1) v += __shfl_down(v, off, 64);
  if (lane == 0){
    int gi = batch[n];
    atomicAdd(&pool[gi], v);
    atomicAdd(&cnt[gi], 1.f);
  }
}

__global__ __launch_bounds__(256) void k_final(const float* __restrict__ pool,
    const float* __restrict__ cnt, const float* __restrict__ predb,
    float* __restrict__ out, int G){
  int g = blockIdx.x*256 + threadIdx.x;
  if (g < G) out[g] = pool[g] / fmaxf(cnt[g], 1.f) + predb[0];
}

// ---------------------------------------------------------------- launcher
extern "C" void kernel_launch(void* const* d_in, const int* in_sizes, int n_in,
                              void* d_out, int out_size, void* d_ws, size_t ws_size,
                              hipStream_t stream){
  const int*   x        = (const int*)d_in[0];
  const int*   eidx     = (const int*)d_in[1];
  const int*   eattr    = (const int*)d_in[2];
  const int*   batch    = (const int*)d_in[3];
  const float* atom_emb = (const float*)d_in[4];
  const float* bond_emb = (const float*)d_in[5];
  const float* W1 = (const float*)d_in[6];
  const float* b1 = (const float*)d_in[7];
  const float* g1 = (const float*)d_in[8];
  const float* be1= (const float*)d_in[9];
  const float* W2 = (const float*)d_in[10];
  const float* b2 = (const float*)d_in[11];
  const float* g2 = (const float*)d_in[12];
  const float* be2= (const float*)d_in[13];
  const float* W3 = (const float*)d_in[14];
  const float* b3 = (const float*)d_in[15];
  const float* tt = (const float*)d_in[16];
  const float* ng = (const float*)d_in[17];
  const float* nb = (const float*)d_in[18];
  const float* predW = (const float*)d_in[19];
  const float* predb = (const float*)d_in[20];
  float* out = (float*)d_out;

  const int N = in_sizes[3];
  const int E = in_sizes[1] / 2;
  const int L = in_sizes[16];
  const int G = out_size;
  const int D = 128, H = 256;

  char* ws = (char*)d_ws;
  size_t off = 0;
  auto carve = [&](size_t bytes)->void*{
    void* p = ws + off;
    off += (bytes + 511) & ~(size_t)511;
    return p;
  };
  // total ~188 MB
  float* h   = (float*)carve((size_t)N*D*4);   // fp32 residual stream
  u16*   h2  = (u16*)  carve((size_t)N*D*2);   // fp16 relu(bn(h))
  u16*   y1  = (u16*)  carve((size_t)N*H*2);   // fp16
  u16*   y2  = (u16*)  carve((size_t)N*H*2);   // fp16
  u16*   hh  = y2;   // hh (fp16, N*D) aliases y2; dead before GEMM2 writes y2
  u16*   Wt1 = (u16*) carve((size_t)L*H*D*2);  // [L][256][128]
  u16*   Wt2 = (u16*) carve((size_t)L*H*H*2);  // [L][256][256]
  u16*   Wt3 = (u16*) carve((size_t)L*D*H*2);  // [L][128][256]
  int*  offs   = (int*)carve((size_t)(N+1)*4);
  int*  cursor = (int*)carve((size_t)N*4);
  int*  cnt    = (int*)carve((size_t)N*4);
  int*  part   = (int*)carve(1024*4);
  int*  esort  = (int*)carve((size_t)E*4);
  float* stats = (float*)carve(1280*4);
  float* s1s = stats,        *s1q = stats + 256;
  float* s2s = stats + 512,  *s2q = stats + 768;
  float* shs = stats + 1024, *shq = stats + 1152;
  float* pool = (float*)carve((size_t)G*4);
  float* cntg = (float*)carve((size_t)G*4);

  int NB = (N + 255) / 256;

  // CSR build (once per call, shared by all 20 layers)
  k_zero_i   <<<NB, 256, 0, stream>>>(cnt, N);
  k_hist     <<<(E+255)/256, 256, 0, stream>>>(eidx + E, E, cnt);
  k_blocksum <<<NB, 256, 0, stream>>>(cnt, N, part);
  k_scanpart <<<1, 1024, 0, stream>>>(part, NB);
  k_scanapply<<<NB, 256, 0, stream>>>(cnt, part, N, E, offs, cursor);
  k_scatter  <<<(E+255)/256, 256, 0, stream>>>(eidx, eidx + E, eattr, E, cursor, esort);
  k_atom     <<<(N+1)/2, 256, 0, stream>>>(x, atom_emb, h, h2, N);

  // weights -> fp16 transposed [Nout][K]
  k_wtrans<<<((L*H*D)+255)/256, 256, 0, stream>>>(W1, Wt1, D, H, L*H*D);
  k_wtrans<<<((L*H*H)+255)/256, 256, 0, stream>>>(W2, Wt2, H, H, L*H*H);
  k_wtrans<<<((L*D*H)+255)/256, 256, 0, stream>>>(W3, Wt3, H, D, L*D*H);

  int mb = (N + 127) / 128;
  for (int l = 0; l < L; ++l){
    if (l > 0){
      k_prenorm<<<(N*D+255)/256, 256, 0, stream>>>(h, h2, shs, shq,
          ng + (size_t)(l-1)*D, nb + (size_t)(l-1)*D, N);
    }
    k_zero_f<<<(1280+255)/256, 256, 0, stream>>>(stats, 1280);
    k_edge  <<<(N+1)/2, 256, 0, stream>>>(h2, offs, esort,
        bond_emb + (size_t)l*3*6*D, tt + l, hh, N);
    // y1 = hh @ W1 + b1   (stats -> s1)
    k_gemm<false,false><<<dim3(mb,2), 256, 0, stream>>>(hh, D,
        Wt1 + (size_t)l*H*D, b1 + (size_t)l*H,
        nullptr, nullptr, nullptr, nullptr, nullptr,
        y1, H, s1s, s1q, N, D);
    // y2 = relu(bn(y1)) @ W2 + b2   (stats -> s2)
    k_gemm<true,false><<<dim3(mb,2), 256, 0, stream>>>(y1, H,
        Wt2 + (size_t)l*H*H, b2 + (size_t)l*H,
        s1s, s1q, g1 + (size_t)l*H, be1 + (size_t)l*H, nullptr,
        y2, H, s2s, s2q, N, H);
    // h = relu(bn(y2)) @ W3 + b3 (+ h residual for l>0)   (stats of new h -> sh)
    k_gemm<true,true><<<dim3(mb,1), 256, 0, stream>>>(y2, H,
        Wt3 + (size_t)l*D*H, b3 + (size_t)l*D,
        s2s, s2q, g2 + (size_t)l*H, be2 + (size_t)l*H,
        (l ? h : nullptr),
        h, D, shs, shq, N, H);
  }

  k_zero_f<<<(G+255)/256, 256, 0, stream>>>(pool, G);
  k_zero_f<<<(G+255)/256, 256, 0, stream>>>(cntg, G);
  k_pool  <<<(N+3)/4, 256, 0, stream>>>(h, shs, shq,
      ng + (size_t)(L-1)*D, nb + (size_t)(L-1)*D, predW, batch, pool, cntg, N);
  k_final <<<(G+255)/256, 256, 0, stream>>>(pool, cntg, predb, out, G);
}

// Round 5
// 6254.162 us; speedup vs baseline: 1.6086x; 1.1342x over previous
//
#include <hip/hip_runtime.h>
#include <math.h>

#define GEPS 1e-7f
#define BNEPS 1e-5f

typedef unsigned short u16;
typedef unsigned int   u32;

typedef _Float16 f16x8 __attribute__((ext_vector_type(8)));
typedef float    f32x4 __attribute__((ext_vector_type(4)));

__device__ __forceinline__ float h2f(u16 u){
  _Float16 x = __builtin_bit_cast(_Float16, u); return (float)x;
}
__device__ __forceinline__ u16 f2h(float f){
  _Float16 x = (_Float16)f; return __builtin_bit_cast(u16, x);
}

// ---------------------------------------------------------------- utilities
__global__ __launch_bounds__(256) void k_zero_i(int* __restrict__ p, int n){
  int i = blockIdx.x*256 + threadIdx.x;
  if (i < n) p[i] = 0;
}
__global__ __launch_bounds__(256) void k_zero_f(float* __restrict__ p, int n){
  int i = blockIdx.x*256 + threadIdx.x;
  if (i < n) p[i] = 0.f;
}

// ---------------------------------------------------------------- CSR build (multi-block scan)
__global__ __launch_bounds__(256) void k_hist(const int* __restrict__ dst, int E,
                                              int* __restrict__ cnt){
  int e = blockIdx.x*256 + threadIdx.x;
  if (e < E) atomicAdd(&cnt[dst[e]], 1);
}

__global__ __launch_bounds__(256) void k_blocksum(const int* __restrict__ cnt, int N,
                                                  int* __restrict__ part){
  __shared__ int s[256];
  int t = threadIdx.x, i = blockIdx.x*256 + t;
  s[t] = (i < N) ? cnt[i] : 0;
  __syncthreads();
  for (int off = 128; off > 0; off >>= 1){
    if (t < off) s[t] += s[t + off];
    __syncthreads();
  }
  if (t == 0) part[blockIdx.x] = s[0];
}

__global__ __launch_bounds__(1024) void k_scanpart(int* __restrict__ part, int NB){
  __shared__ int s[1024];
  int t = threadIdx.x;
  int v = (t < NB) ? part[t] : 0;
  s[t] = v;
  __syncthreads();
  for (int off = 1; off < 1024; off <<= 1){
    int u = (t >= off) ? s[t-off] : 0;
    __syncthreads();
    s[t] += u;
    __syncthreads();
  }
  if (t < NB) part[t] = s[t] - v;   // exclusive
}

__global__ __launch_bounds__(256) void k_scanapply(const int* __restrict__ cnt,
    const int* __restrict__ part, int N, int E,
    int* __restrict__ offs, int* __restrict__ cursor){
  __shared__ int s[256];
  int t = threadIdx.x, i = blockIdx.x*256 + t;
  int v = (i < N) ? cnt[i] : 0;
  s[t] = v;
  __syncthreads();
  for (int off = 1; off < 256; off <<= 1){
    int u = (t >= off) ? s[t-off] : 0;
    __syncthreads();
    s[t] += u;
    __syncthreads();
  }
  int ex = part[blockIdx.x] + s[t] - v;
  if (i < N){
    offs[i]   = ex;
    cursor[i] = ex;
    if (i == N-1) offs[N] = ex + v;
  }
}

__global__ __launch_bounds__(256) void k_scatter(const int* __restrict__ src,
    const int* __restrict__ dst, const int* __restrict__ attr, int E,
    int* __restrict__ cursor, int* __restrict__ esort){
  int e = blockIdx.x*256 + threadIdx.x;
  if (e >= E) return;
  int d = dst[e];
  int pos = atomicAdd(&cursor[d], 1);
  int a = (src[e] & 0x1ffff)
        | ((attr[3*(size_t)e]   & 15) << 17)
        | ((attr[3*(size_t)e+1] & 15) << 21)
        | ((attr[3*(size_t)e+2] & 15) << 25);
  esort[pos] = a;
}

// ---------------------------------------------------------------- weight prep: fp32 [L][K][N] -> fp16 [L][N][K]
__global__ __launch_bounds__(256) void k_wtrans(const float* __restrict__ W,
    u16* __restrict__ Wt, int K, int Nout, int total){
  int id = blockIdx.x*256 + threadIdx.x;
  if (id >= total) return;
  int k   = id % K;
  int rem = id / K;
  int n   = rem % Nout;
  int l   = rem / Nout;
  Wt[id] = f2h(W[((size_t)l*K + k)*Nout + n]);
}

// ---------------------------------------------------------------- atom encoder
__global__ __launch_bounds__(256) void k_atom(const int* __restrict__ x,
    const float* __restrict__ emb, float* __restrict__ h, int N){
  int d = threadIdx.x & 127;
  int n = (blockIdx.x << 1) + (threadIdx.x >> 7);
  if (n >= N) return;
  float s = 0.f;
  #pragma unroll
  for (int i = 0; i < 9; ++i){
    int idx = x[(size_t)n*9 + i];
    s += emb[((size_t)i*119 + idx)*128 + d];
  }
  h[(size_t)n*128 + d] = s;
}

// ---------------------------------------------------------------- fused edge pass:
// reads fp32 h directly, applies relu(bn(.)) inline (PRE_BN) from batch stats, one-pass
// softmax (no max subtraction: arguments bounded ~8 by the preceding BN; exp overflows
// only past 88), writes hh = transformed(h[n]) + aggregated msg as fp16.
// 1 wave per node, 2 channels per thread.
template<bool PRE_BN>
__global__ __launch_bounds__(256)
void k_edge(const float* __restrict__ h,
    const int* __restrict__ offs, const int* __restrict__ esort,
    const float* __restrict__ bond,   // [3][6][128] for this layer
    const float* __restrict__ tptr,
    const float* __restrict__ ssum_, const float* __restrict__ ssq_,
    const float* __restrict__ g, const float* __restrict__ b,
    u16* __restrict__ hh, int N, float invN){
  __shared__ float sg[128], sv[128];
  int tid = threadIdx.x;
  if (PRE_BN){
    if (tid < 128){
      float mu  = ssum_[tid]*invN;
      float var = fmaxf(ssq_[tid]*invN - mu*mu, 0.f);
      float rs  = rsqrtf(var + BNEPS);
      float s   = g[tid]*rs;
      sg[tid] = s;
      sv[tid] = b[tid] - mu*s;
    }
    __syncthreads();
  }
  int lane = tid & 63;
  int n = (blockIdx.x << 2) + (tid >> 6);
  if (n >= N) return;
  int c0 = lane << 1;
  float tl = *tptr;
  float sg0=1.f, sv0=0.f, sg1=1.f, sv1=0.f;
  if (PRE_BN){ sg0=sg[c0]; sv0=sv[c0]; sg1=sg[c0+1]; sv1=sv[c0+1]; }

  int s0 = offs[n], s1 = offs[n+1];
  float den0 = 0.f, acc0 = 0.f, den1 = 0.f, acc1 = 0.f;
  for (int e = s0; e < s1; ++e){
    int se = esort[e];
    int sidx = se & 0x1ffff;
    int a0 = (se >> 17) & 15, a1 = (se >> 21) & 15, a2 = (se >> 25) & 15;
    float2 hv = *(const float2*)(h + (size_t)sidx*128 + c0);
    float x0 = hv.x, x1 = hv.y;
    if (PRE_BN){
      x0 = fmaxf(x0*sg0 + sv0, 0.f);
      x1 = fmaxf(x1*sg1 + sv1, 0.f);
    }
    float2 e0 = *(const float2*)(bond + a0*128 + c0);
    float2 e1 = *(const float2*)(bond + (6 + a1)*128 + c0);
    float2 e2 = *(const float2*)(bond + (12 + a2)*128 + c0);
    float m0 = fmaxf(x0 + e0.x + e1.x + e2.x, 0.f) + GEPS;
    float m1 = fmaxf(x1 + e0.y + e1.y + e2.y, 0.f) + GEPS;
    float p0 = __expf(m0*tl);
    float p1 = __expf(m1*tl);
    den0 += p0; acc0 += p0*m0;
    den1 += p1; acc1 += p1*m1;
  }
  float2 hv = *(const float2*)(h + (size_t)n*128 + c0);
  float x0 = hv.x, x1 = hv.y;
  if (PRE_BN){
    x0 = fmaxf(x0*sg0 + sv0, 0.f);
    x1 = fmaxf(x1*sg1 + sv1, 0.f);
  }
  float r0 = x0 + acc0 / fmaxf(den0, GEPS);   // empty segment -> +0
  float r1 = x1 + acc1 / fmaxf(den1, GEPS);
  u32 pk = (u32)f2h(r0) | ((u32)f2h(r1) << 16);
  *((u32*)hh + (size_t)n*64 + lane) = pk;
}

// ---------------------------------------------------------------- MFMA fp16 GEMM, 128x128 tile
template<bool TRANSFORM, bool OUT32>
__global__ __launch_bounds__(256)
void k_gemm(const u16* __restrict__ A, int lda,
            const u16* __restrict__ Wt,
            const float* __restrict__ bias,
            const float* __restrict__ sIn, const float* __restrict__ qIn,
            const float* __restrict__ gam, const float* __restrict__ bet,
            const float* __restrict__ resid,
            void* __restrict__ outv, int ldo,
            float* __restrict__ sOut, float* __restrict__ qOut,
            int M, int K){
  __shared__ __align__(16) _Float16 As[128][40];   // pitch 40 f16 = 80B
  __shared__ __align__(16) _Float16 Bs[128][40];
  __shared__ float sc[256], shv[256];
  __shared__ float sumc[128], sqc[128];

  int tid = threadIdx.x;
  if (TRANSFORM){
    float inv = 1.f / (float)M;
    for (int k = tid; k < K; k += 256){
      float mu  = sIn[k]*inv;
      float var = fmaxf(qIn[k]*inv - mu*mu, 0.f);
      float rs  = rsqrtf(var + BNEPS);
      float s   = gam[k]*rs;
      sc[k]  = s;
      shv[k] = bet[k] - mu*s;
    }
    __syncthreads();
  }

  int mBase = blockIdx.x * 128;
  int cBase = blockIdx.y * 128;
  int w    = tid >> 6;
  int lane = tid & 63;
  int wm = w & 1, wn = w >> 1;
  int quad = lane >> 4, ln = lane & 15;

  f32x4 acc[4][4];
  #pragma unroll
  for (int i = 0; i < 4; ++i)
    #pragma unroll
    for (int j = 0; j < 4; ++j)
      acc[i][j] = (f32x4){0.f,0.f,0.f,0.f};

  int kTiles = K >> 5;
  for (int kt = 0; kt < kTiles; ++kt){
    int k0 = kt << 5;
    #pragma unroll
    for (int s = 0; s < 2; ++s){
      int idx = s*256 + tid;
      int row = idx >> 2;
      int seg = (idx & 3) << 3;
      int gr = mBase + row; if (gr >= M) gr = M - 1;
      uint4 ra = *(const uint4*)(A + (size_t)gr*lda + k0 + seg);
      if (TRANSFORM){
        int kb = k0 + seg;
        float f0 = fmaxf(h2f((u16)(ra.x & 0xffff))*sc[kb+0] + shv[kb+0], 0.f);
        float f1 = fmaxf(h2f((u16)(ra.x >> 16)) *sc[kb+1] + shv[kb+1], 0.f);
        float f2 = fmaxf(h2f((u16)(ra.y & 0xffff))*sc[kb+2] + shv[kb+2], 0.f);
        float f3 = fmaxf(h2f((u16)(ra.y >> 16)) *sc[kb+3] + shv[kb+3], 0.f);
        float f4 = fmaxf(h2f((u16)(ra.z & 0xffff))*sc[kb+4] + shv[kb+4], 0.f);
        float f5 = fmaxf(h2f((u16)(ra.z >> 16)) *sc[kb+5] + shv[kb+5], 0.f);
        float f6 = fmaxf(h2f((u16)(ra.w & 0xffff))*sc[kb+6] + shv[kb+6], 0.f);
        float f7 = fmaxf(h2f((u16)(ra.w >> 16)) *sc[kb+7] + shv[kb+7], 0.f);
        ra.x = (u32)f2h(f0) | ((u32)f2h(f1) << 16);
        ra.y = (u32)f2h(f2) | ((u32)f2h(f3) << 16);
        ra.z = (u32)f2h(f4) | ((u32)f2h(f5) << 16);
        ra.w = (u32)f2h(f6) | ((u32)f2h(f7) << 16);
      }
      *(uint4*)(&As[row][seg]) = ra;
      uint4 rb = *(const uint4*)(Wt + (size_t)(cBase + row)*K + k0 + seg);
      *(uint4*)(&Bs[row][seg]) = rb;
    }
    __syncthreads();

    f16x8 af[4], bf[4];
    #pragma unroll
    for (int i = 0; i < 4; ++i)
      af[i] = *(const f16x8*)(&As[64*wm + 16*i + ln][quad*8]);
    #pragma unroll
    for (int j = 0; j < 4; ++j)
      bf[j] = *(const f16x8*)(&Bs[64*wn + 16*j + ln][quad*8]);
    #pragma unroll
    for (int i = 0; i < 4; ++i)
      #pragma unroll
      for (int j = 0; j < 4; ++j)
        acc[i][j] = __builtin_amdgcn_mfma_f32_16x16x32_f16(af[i], bf[j], acc[i][j], 0, 0, 0);
    __syncthreads();
  }

  float bv[4];
  #pragma unroll
  for (int j = 0; j < 4; ++j) bv[j] = bias[cBase + 64*wn + 16*j + ln];
  float ps[4] = {0,0,0,0}, pq[4] = {0,0,0,0};

  #pragma unroll
  for (int i = 0; i < 4; ++i){
    int rbase = mBase + 64*wm + 16*i + quad*4;
    #pragma unroll
    for (int r = 0; r < 4; ++r){
      int row = rbase + r;
      if (row < M){
        #pragma unroll
        for (int j = 0; j < 4; ++j){
          int col = cBase + 64*wn + 16*j + ln;
          size_t off = (size_t)row*ldo + col;
          float v = acc[i][j][r] + bv[j];
          if (OUT32){
            float* out = (float*)outv;
            if (resid) v += resid[off];
            out[off] = v;
            ps[j] += v; pq[j] += v*v;
          } else {
            u16* out = (u16*)outv;
            u16 q = f2h(v);
            out[off] = q;
            float vr = h2f(q);
            ps[j] += vr; pq[j] += vr*vr;
          }
        }
      }
    }
  }
  __syncthreads();
  if (tid < 128){ sumc[tid] = 0.f; sqc[tid] = 0.f; }
  __syncthreads();
  #pragma unroll
  for (int j = 0; j < 4; ++j){
    int cl = 64*wn + 16*j + ln;
    atomicAdd(&sumc[cl], ps[j]);
    atomicAdd(&sqc[cl],  pq[j]);
  }
  __syncthreads();
  if (tid < 128){
    atomicAdd(&sOut[cBase + tid], sumc[tid]);
    atomicAdd(&qOut[cBase + tid], sqc[tid]);
  }
}

// ---------------------------------------------------------------- pooling
__global__ __launch_bounds__(256) void k_pool(const float* __restrict__ h,
    const float* __restrict__ ssum, const float* __restrict__ ssq,
    const float* __restrict__ g, const float* __restrict__ b,
    const float* __restrict__ predW, const int* __restrict__ batch,
    float* __restrict__ pool, float* __restrict__ cnt, int N){
  int lane = threadIdx.x & 63;
  int n = (blockIdx.x << 2) + (threadIdx.x >> 6);
  if (n >= N) return;
  float inv = 1.f / (float)N;
  float v = 0.f;
  #pragma unroll
  for (int d = lane; d < 128; d += 64){
    float mu  = ssum[d]*inv;
    float var = fmaxf(ssq[d]*inv - mu*mu, 0.f);
    float rs  = rsqrtf(var + BNEPS);
    float bn  = (h[(size_t)n*128 + d] - mu)*(g[d]*rs) + b[d];
    v += bn * predW[d];
  }
  #pragma unroll
  for (int off = 32; off > 0; off >>= 1) v += __shfl_down(v, off, 64);
  if (lane == 0){
    int gi = batch[n];
    atomicAdd(&pool[gi], v);
    atomicAdd(&cnt[gi], 1.f);
  }
}

__global__ __launch_bounds__(256) void k_final(const float* __restrict__ pool,
    const float* __restrict__ cnt, const float* __restrict__ predb,
    float* __restrict__ out, int G){
  int g = blockIdx.x*256 + threadIdx.x;
  if (g < G) out[g] = pool[g] / fmaxf(cnt[g], 1.f) + predb[0];
}

// ---------------------------------------------------------------- launcher
extern "C" void kernel_launch(void* const* d_in, const int* in_sizes, int n_in,
                              void* d_out, int out_size, void* d_ws, size_t ws_size,
                              hipStream_t stream){
  const int*   x        = (const int*)d_in[0];
  const int*   eidx     = (const int*)d_in[1];
  const int*   eattr    = (const int*)d_in[2];
  const int*   batch    = (const int*)d_in[3];
  const float* atom_emb = (const float*)d_in[4];
  const float* bond_emb = (const float*)d_in[5];
  const float* W1 = (const float*)d_in[6];
  const float* b1 = (const float*)d_in[7];
  const float* g1 = (const float*)d_in[8];
  const float* be1= (const float*)d_in[9];
  const float* W2 = (const float*)d_in[10];
  const float* b2 = (const float*)d_in[11];
  const float* g2 = (const float*)d_in[12];
  const float* be2= (const float*)d_in[13];
  const float* W3 = (const float*)d_in[14];
  const float* b3 = (const float*)d_in[15];
  const float* tt = (const float*)d_in[16];
  const float* ng = (const float*)d_in[17];
  const float* nb = (const float*)d_in[18];
  const float* predW = (const float*)d_in[19];
  const float* predb = (const float*)d_in[20];
  float* out = (float*)d_out;

  const int N = in_sizes[3];
  const int E = in_sizes[1] / 2;
  const int L = in_sizes[16];
  const int G = out_size;
  const int D = 128, H = 256;
  const float invN = 1.f / (float)N;

  char* ws = (char*)d_ws;
  size_t off = 0;
  auto carve = [&](size_t bytes)->void*{
    void* p = ws + off;
    off += (bytes + 511) & ~(size_t)511;
    return p;
  };
  // total ~162 MB
  float* h   = (float*)carve((size_t)N*D*4);   // fp32 residual stream
  u16*   y1  = (u16*)  carve((size_t)N*H*2);   // fp16
  u16*   y2  = (u16*)  carve((size_t)N*H*2);   // fp16
  u16*   hh  = y2;   // hh (fp16, N*D) aliases y2; dead before GEMM2 writes y2
  u16*   Wt1 = (u16*) carve((size_t)L*H*D*2);  // [L][256][128]
  u16*   Wt2 = (u16*) carve((size_t)L*H*H*2);  // [L][256][256]
  u16*   Wt3 = (u16*) carve((size_t)L*D*H*2);  // [L][128][256]
  int*  offs   = (int*)carve((size_t)(N+1)*4);
  int*  cursor = (int*)carve((size_t)N*4);
  int*  cnt    = (int*)carve((size_t)N*4);
  int*  part   = (int*)carve(1024*4);
  int*  esort  = (int*)carve((size_t)E*4);
  float* stats = (float*)carve((size_t)L*1280*4);   // per-layer: s1(512) s2(512) sh(256)
  float* pool = (float*)carve((size_t)G*4);
  float* cntg = (float*)carve((size_t)G*4);

  int NB = (N + 255) / 256;

  // CSR build (once per call, shared by all 20 layers)
  k_zero_i   <<<NB, 256, 0, stream>>>(cnt, N);
  k_hist     <<<(E+255)/256, 256, 0, stream>>>(eidx + E, E, cnt);
  k_blocksum <<<NB, 256, 0, stream>>>(cnt, N, part);
  k_scanpart <<<1, 1024, 0, stream>>>(part, NB);
  k_scanapply<<<NB, 256, 0, stream>>>(cnt, part, N, E, offs, cursor);
  k_scatter  <<<(E+255)/256, 256, 0, stream>>>(eidx, eidx + E, eattr, E, cursor, esort);
  k_atom     <<<(N+1)/2, 256, 0, stream>>>(x, atom_emb, h, N);
  k_zero_f   <<<(L*1280+255)/256, 256, 0, stream>>>(stats, L*1280);

  // weights -> fp16 transposed [Nout][K]
  k_wtrans<<<((L*H*D)+255)/256, 256, 0, stream>>>(W1, Wt1, D, H, L*H*D);
  k_wtrans<<<((L*H*H)+255)/256, 256, 0, stream>>>(W2, Wt2, H, H, L*H*H);
  k_wtrans<<<((L*D*H)+255)/256, 256, 0, stream>>>(W3, Wt3, H, D, L*D*H);

  int mb = (N + 127) / 128;
  int eb = (N + 3) / 4;
  for (int l = 0; l < L; ++l){
    float* st  = stats + (size_t)l*1280;
    float* s1s = st,        *s1q = st + 256;
    float* s2s = st + 512,  *s2q = st + 768;
    float* shs = st + 1024, *shq = st + 1152;
    const float* bondl = bond_emb + (size_t)l*3*6*D;
    if (l == 0){
      k_edge<false><<<eb, 256, 0, stream>>>(h, offs, esort, bondl, tt + l,
          nullptr, nullptr, nullptr, nullptr, hh, N, invN);
    } else {
      float* stp = stats + (size_t)(l-1)*1280;
      k_edge<true><<<eb, 256, 0, stream>>>(h, offs, esort, bondl, tt + l,
          stp + 1024, stp + 1152, ng + (size_t)(l-1)*D, nb + (size_t)(l-1)*D,
          hh, N, invN);
    }
    // y1 = hh @ W1 + b1   (stats -> s1)
    k_gemm<false,false><<<dim3(mb,2), 256, 0, stream>>>(hh, D,
        Wt1 + (size_t)l*H*D, b1 + (size_t)l*H,
        nullptr, nullptr, nullptr, nullptr, nullptr,
        y1, H, s1s, s1q, N, D);
    // y2 = relu(bn(y1)) @ W2 + b2   (stats -> s2)
    k_gemm<true,false><<<dim3(mb,2), 256, 0, stream>>>(y1, H,
        Wt2 + (size_t)l*H*H, b2 + (size_t)l*H,
        s1s, s1q, g1 + (size_t)l*H, be1 + (size_t)l*H, nullptr,
        y2, H, s2s, s2q, N, H);
    // h = relu(bn(y2)) @ W3 + b3 (+ h residual for l>0)   (stats of new h -> sh)
    k_gemm<true,true><<<dim3(mb,1), 256, 0, stream>>>(y2, H,
        Wt3 + (size_t)l*D*H, b3 + (size_t)l*D,
        s2s, s2q, g2 + (size_t)l*H, be2 + (size_t)l*H,
        (l ? h : nullptr),
        h, D, shs, shq, N, H);
  }

  float* stL = stats + (size_t)(L-1)*1280;
  k_zero_f<<<(G+255)/256, 256, 0, stream>>>(pool, G);
  k_zero_f<<<(G+255)/256, 256, 0, stream>>>(cntg, G);
  k_pool  <<<(N+3)/4, 256, 0, stream>>>(h, stL + 1024, stL + 1152,
      ng + (size_t)(L-1)*D, nb + (size_t)(L-1)*D, predW, batch, pool, cntg, N);
  k_final <<<(G+255)/256, 256, 0, stream>>>(pool, cntg, predb, out, G);
}

// Round 6
// 5931.241 us; speedup vs baseline: 1.6961x; 1.0544x over previous
//
#include <hip/hip_runtime.h>
#include <math.h>

#define GEPS 1e-7f
#define BNEPS 1e-5f

typedef unsigned short u16;
typedef unsigned int   u32;

typedef _Float16 f16x8 __attribute__((ext_vector_type(8)));
typedef float    f32x4 __attribute__((ext_vector_type(4)));

__device__ __forceinline__ float h2f(u16 u){
  _Float16 x = __builtin_bit_cast(_Float16, u); return (float)x;
}
__device__ __forceinline__ u16 f2h(float f){
  _Float16 x = (_Float16)f; return __builtin_bit_cast(u16, x);
}

// ---------------------------------------------------------------- utilities
__global__ __launch_bounds__(256) void k_zero_i(int* __restrict__ p, int n){
  int i = blockIdx.x*256 + threadIdx.x;
  if (i < n) p[i] = 0;
}
__global__ __launch_bounds__(256) void k_zero_f(float* __restrict__ p, int n){
  int i = blockIdx.x*256 + threadIdx.x;
  if (i < n) p[i] = 0.f;
}

// ---------------------------------------------------------------- CSR build (multi-block scan)
__global__ __launch_bounds__(256) void k_hist(const int* __restrict__ dst, int E,
                                              int* __restrict__ cnt){
  int e = blockIdx.x*256 + threadIdx.x;
  if (e < E) atomicAdd(&cnt[dst[e]], 1);
}

__global__ __launch_bounds__(256) void k_blocksum(const int* __restrict__ cnt, int N,
                                                  int* __restrict__ part){
  __shared__ int s[256];
  int t = threadIdx.x, i = blockIdx.x*256 + t;
  s[t] = (i < N) ? cnt[i] : 0;
  __syncthreads();
  for (int off = 128; off > 0; off >>= 1){
    if (t < off) s[t] += s[t + off];
    __syncthreads();
  }
  if (t == 0) part[blockIdx.x] = s[0];
}

__global__ __launch_bounds__(1024) void k_scanpart(int* __restrict__ part, int NB){
  __shared__ int s[1024];
  int t = threadIdx.x;
  int v = (t < NB) ? part[t] : 0;
  s[t] = v;
  __syncthreads();
  for (int off = 1; off < 1024; off <<= 1){
    int u = (t >= off) ? s[t-off] : 0;
    __syncthreads();
    s[t] += u;
    __syncthreads();
  }
  if (t < NB) part[t] = s[t] - v;   // exclusive
}

__global__ __launch_bounds__(256) void k_scanapply(const int* __restrict__ cnt,
    const int* __restrict__ part, int N, int E,
    int* __restrict__ offs, int* __restrict__ cursor){
  __shared__ int s[256];
  int t = threadIdx.x, i = blockIdx.x*256 + t;
  int v = (i < N) ? cnt[i] : 0;
  s[t] = v;
  __syncthreads();
  for (int off = 1; off < 256; off <<= 1){
    int u = (t >= off) ? s[t-off] : 0;
    __syncthreads();
    s[t] += u;
    __syncthreads();
  }
  int ex = part[blockIdx.x] + s[t] - v;
  if (i < N){
    offs[i]   = ex;
    cursor[i] = ex;
    if (i == N-1) offs[N] = ex + v;
  }
}

__global__ __launch_bounds__(256) void k_scatter(const int* __restrict__ src,
    const int* __restrict__ dst, const int* __restrict__ attr, int E,
    int* __restrict__ cursor, int* __restrict__ esort){
  int e = blockIdx.x*256 + threadIdx.x;
  if (e >= E) return;
  int d = dst[e];
  int pos = atomicAdd(&cursor[d], 1);
  int a = (src[e] & 0x1ffff)
        | ((attr[3*(size_t)e]   & 15) << 17)
        | ((attr[3*(size_t)e+1] & 15) << 21)
        | ((attr[3*(size_t)e+2] & 15) << 25);
  esort[pos] = a;
}

// ---------------------------------------------------------------- weight prep: fp32 [L][K][N] -> fp16 [L][N][K]
__global__ __launch_bounds__(256) void k_wtrans(const float* __restrict__ W,
    u16* __restrict__ Wt, int K, int Nout, int total){
  int id = blockIdx.x*256 + threadIdx.x;
  if (id >= total) return;
  int k   = id % K;
  int rem = id / K;
  int n   = rem % Nout;
  int l   = rem / Nout;
  Wt[id] = f2h(W[((size_t)l*K + k)*Nout + n]);
}

// ---------------------------------------------------------------- atom encoder
__global__ __launch_bounds__(256) void k_atom(const int* __restrict__ x,
    const float* __restrict__ emb, float* __restrict__ h, int N){
  int d = threadIdx.x & 127;
  int n = (blockIdx.x << 1) + (threadIdx.x >> 7);
  if (n >= N) return;
  float s = 0.f;
  #pragma unroll
  for (int i = 0; i < 9; ++i){
    int idx = x[(size_t)n*9 + i];
    s += emb[((size_t)i*119 + idx)*128 + d];
  }
  h[(size_t)n*128 + d] = s;
}

// ---------------------------------------------------------------- fused edge pass:
// relu(bn(.)) inline from batch stats, one-pass softmax (args bounded ~8 by BN),
// software-pipelined: edge e+1's esort/h/bond rows prefetched while computing edge e.
template<bool PRE_BN>
__global__ __launch_bounds__(256)
void k_edge(const float* __restrict__ h,
    const int* __restrict__ offs, const int* __restrict__ esort,
    const float* __restrict__ bond,   // [3][6][128] for this layer
    const float* __restrict__ tptr,
    const float* __restrict__ ssum_, const float* __restrict__ ssq_,
    const float* __restrict__ g, const float* __restrict__ b,
    u16* __restrict__ hh, int N, float invN){
  __shared__ float sg[128], sv[128];
  int tid = threadIdx.x;
  if (PRE_BN){
    if (tid < 128){
      float mu  = ssum_[tid]*invN;
      float var = fmaxf(ssq_[tid]*invN - mu*mu, 0.f);
      float rs  = rsqrtf(var + BNEPS);
      float s   = g[tid]*rs;
      sg[tid] = s;
      sv[tid] = b[tid] - mu*s;
    }
    __syncthreads();
  }
  int lane = tid & 63;
  int n = (blockIdx.x << 2) + (tid >> 6);
  if (n >= N) return;
  int c0 = lane << 1;
  float tl = *tptr;
  float sg0=1.f, sv0=0.f, sg1=1.f, sv1=0.f;
  if (PRE_BN){ sg0=sg[c0]; sv0=sv[c0]; sg1=sg[c0+1]; sv1=sv[c0+1]; }

  int s0 = offs[n], s1 = offs[n+1];
  float den0 = 0.f, acc0 = 0.f, den1 = 0.f, acc1 = 0.f;
  if (s0 < s1){
    int se = esort[s0];
    int sidx = se & 0x1ffff;
    float2 hv = *(const float2*)(h + (size_t)sidx*128 + c0);
    float2 e0 = *(const float2*)(bond + ((se>>17)&15)*128 + c0);
    float2 e1 = *(const float2*)(bond + (6 + ((se>>21)&15))*128 + c0);
    float2 e2 = *(const float2*)(bond + (12 + ((se>>25)&15))*128 + c0);
    for (int e = s0; e < s1; ++e){
      float2 hvN = hv, e0N = e0, e1N = e1, e2N = e2;
      if (e + 1 < s1){                 // prefetch next edge's rows
        int seN = esort[e+1];
        int sidxN = seN & 0x1ffff;
        hvN = *(const float2*)(h + (size_t)sidxN*128 + c0);
        e0N = *(const float2*)(bond + ((seN>>17)&15)*128 + c0);
        e1N = *(const float2*)(bond + (6 + ((seN>>21)&15))*128 + c0);
        e2N = *(const float2*)(bond + (12 + ((seN>>25)&15))*128 + c0);
      }
      float x0 = hv.x, x1 = hv.y;
      if (PRE_BN){
        x0 = fmaxf(x0*sg0 + sv0, 0.f);
        x1 = fmaxf(x1*sg1 + sv1, 0.f);
      }
      float m0 = fmaxf(x0 + e0.x + e1.x + e2.x, 0.f) + GEPS;
      float m1 = fmaxf(x1 + e0.y + e1.y + e2.y, 0.f) + GEPS;
      float p0 = __expf(m0*tl);
      float p1 = __expf(m1*tl);
      den0 += p0; acc0 += p0*m0;
      den1 += p1; acc1 += p1*m1;
      hv = hvN; e0 = e0N; e1 = e1N; e2 = e2N;
    }
  }
  float2 hv = *(const float2*)(h + (size_t)n*128 + c0);
  float x0 = hv.x, x1 = hv.y;
  if (PRE_BN){
    x0 = fmaxf(x0*sg0 + sv0, 0.f);
    x1 = fmaxf(x1*sg1 + sv1, 0.f);
  }
  float r0 = x0 + acc0 / fmaxf(den0, GEPS);   // empty segment -> +0
  float r1 = x1 + acc1 / fmaxf(den1, GEPS);
  u32 pk = (u32)f2h(r0) | ((u32)f2h(r1) << 16);
  *((u32*)hh + (size_t)n*64 + lane) = pk;
}

// ---------------------------------------------------------------- MFMA fp16 GEMM, 128x128 tile,
// double-buffered LDS: tile k+1 loaded into registers while tile k's MFMAs run,
// one barrier per K-tile.
template<bool TRANSFORM, bool OUT32>
__global__ __launch_bounds__(256)
void k_gemm(const u16* __restrict__ A, int lda,
            const u16* __restrict__ Wt,
            const float* __restrict__ bias,
            const float* __restrict__ sIn, const float* __restrict__ qIn,
            const float* __restrict__ gam, const float* __restrict__ bet,
            const float* __restrict__ resid,
            void* __restrict__ outv, int ldo,
            float* __restrict__ sOut, float* __restrict__ qOut,
            int M, int K){
  __shared__ __align__(16) _Float16 As[2][128][40];   // pitch 40 f16 = 80B
  __shared__ __align__(16) _Float16 Bs[2][128][40];
  __shared__ float sc[256], shv[256];
  __shared__ float sumc[128], sqc[128];

  int tid = threadIdx.x;
  if (TRANSFORM){
    float inv = 1.f / (float)M;
    for (int k = tid; k < K; k += 256){
      float mu  = sIn[k]*inv;
      float var = fmaxf(qIn[k]*inv - mu*mu, 0.f);
      float rs  = rsqrtf(var + BNEPS);
      float s   = gam[k]*rs;
      sc[k]  = s;
      shv[k] = bet[k] - mu*s;
    }
    __syncthreads();
  }

  int mBase = blockIdx.x * 128;
  int cBase = blockIdx.y * 128;
  int w    = tid >> 6;
  int lane = tid & 63;
  int wm = w & 1, wn = w >> 1;
  int quad = lane >> 4, ln = lane & 15;

  // staging geometry: idx in [0,512): row = idx>>2, seg = (idx&3)*8 halves
  int r0i = tid >> 1;            // s=0 row? no: idx=s*256+tid -> rows tid>>2 and 64+tid>>2
  (void)r0i;
  int srow0 = tid >> 2,          sseg0 = (tid & 3) << 3;
  int srow1 = 64 + (tid >> 2),   sseg1 = sseg0;
  int gr0 = mBase + srow0; if (gr0 >= M) gr0 = M - 1;
  int gr1 = mBase + srow1; if (gr1 >= M) gr1 = M - 1;
  const u16* a0p = A + (size_t)gr0*lda + sseg0;
  const u16* a1p = A + (size_t)gr1*lda + sseg1;
  const u16* b0p = Wt + (size_t)(cBase + srow0)*K + sseg0;
  const u16* b1p = Wt + (size_t)(cBase + srow1)*K + sseg1;

  f32x4 acc[4][4];
  #pragma unroll
  for (int i = 0; i < 4; ++i)
    #pragma unroll
    for (int j = 0; j < 4; ++j)
      acc[i][j] = (f32x4){0.f,0.f,0.f,0.f};

  uint4 pa0, pa1, pb0, pb1;
  pa0 = *(const uint4*)(a0p);
  pa1 = *(const uint4*)(a1p);
  pb0 = *(const uint4*)(b0p);
  pb1 = *(const uint4*)(b1p);

  auto xform = [&](uint4 ra, int kb)->uint4{
    float f0 = fmaxf(h2f((u16)(ra.x & 0xffff))*sc[kb+0] + shv[kb+0], 0.f);
    float f1 = fmaxf(h2f((u16)(ra.x >> 16)) *sc[kb+1] + shv[kb+1], 0.f);
    float f2 = fmaxf(h2f((u16)(ra.y & 0xffff))*sc[kb+2] + shv[kb+2], 0.f);
    float f3 = fmaxf(h2f((u16)(ra.y >> 16)) *sc[kb+3] + shv[kb+3], 0.f);
    float f4 = fmaxf(h2f((u16)(ra.z & 0xffff))*sc[kb+4] + shv[kb+4], 0.f);
    float f5 = fmaxf(h2f((u16)(ra.z >> 16)) *sc[kb+5] + shv[kb+5], 0.f);
    float f6 = fmaxf(h2f((u16)(ra.w & 0xffff))*sc[kb+6] + shv[kb+6], 0.f);
    float f7 = fmaxf(h2f((u16)(ra.w >> 16)) *sc[kb+7] + shv[kb+7], 0.f);
    uint4 o;
    o.x = (u32)f2h(f0) | ((u32)f2h(f1) << 16);
    o.y = (u32)f2h(f2) | ((u32)f2h(f3) << 16);
    o.z = (u32)f2h(f4) | ((u32)f2h(f5) << 16);
    o.w = (u32)f2h(f6) | ((u32)f2h(f7) << 16);
    return o;
  };

  // write tile 0 to buffer 0
  {
    uint4 wa0 = TRANSFORM ? xform(pa0, sseg0) : pa0;
    uint4 wa1 = TRANSFORM ? xform(pa1, sseg1) : pa1;
    *(uint4*)(&As[0][srow0][sseg0]) = wa0;
    *(uint4*)(&As[0][srow1][sseg1]) = wa1;
    *(uint4*)(&Bs[0][srow0][sseg0]) = pb0;
    *(uint4*)(&Bs[0][srow1][sseg1]) = pb1;
  }

  int kTiles = K >> 5;
  for (int kt = 0; kt < kTiles; ++kt){
    __syncthreads();
    int cb = kt & 1, nb = cb ^ 1;
    int k1 = (kt + 1) << 5;
    if (kt + 1 < kTiles){               // issue next tile's loads early
      pa0 = *(const uint4*)(a0p + k1);
      pa1 = *(const uint4*)(a1p + k1);
      pb0 = *(const uint4*)(b0p + k1);
      pb1 = *(const uint4*)(b1p + k1);
    }
    f16x8 af[4], bf[4];
    #pragma unroll
    for (int i = 0; i < 4; ++i)
      af[i] = *(const f16x8*)(&As[cb][64*wm + 16*i + ln][quad*8]);
    #pragma unroll
    for (int j = 0; j < 4; ++j)
      bf[j] = *(const f16x8*)(&Bs[cb][64*wn + 16*j + ln][quad*8]);
    #pragma unroll
    for (int i = 0; i < 4; ++i)
      #pragma unroll
      for (int j = 0; j < 4; ++j)
        acc[i][j] = __builtin_amdgcn_mfma_f32_16x16x32_f16(af[i], bf[j], acc[i][j], 0, 0, 0);
    if (kt + 1 < kTiles){               // stage next tile into alternate buffer
      uint4 wa0 = TRANSFORM ? xform(pa0, k1 + sseg0) : pa0;
      uint4 wa1 = TRANSFORM ? xform(pa1, k1 + sseg1) : pa1;
      *(uint4*)(&As[nb][srow0][sseg0]) = wa0;
      *(uint4*)(&As[nb][srow1][sseg1]) = wa1;
      *(uint4*)(&Bs[nb][srow0][sseg0]) = pb0;
      *(uint4*)(&Bs[nb][srow1][sseg1]) = pb1;
    }
  }

  float bv[4];
  #pragma unroll
  for (int j = 0; j < 4; ++j) bv[j] = bias[cBase + 64*wn + 16*j + ln];
  float ps[4] = {0,0,0,0}, pq[4] = {0,0,0,0};

  #pragma unroll
  for (int i = 0; i < 4; ++i){
    int rbase = mBase + 64*wm + 16*i + quad*4;
    #pragma unroll
    for (int r = 0; r < 4; ++r){
      int row = rbase + r;
      if (row < M){
        #pragma unroll
        for (int j = 0; j < 4; ++j){
          int col = cBase + 64*wn + 16*j + ln;
          size_t off = (size_t)row*ldo + col;
          float v = acc[i][j][r] + bv[j];
          if (OUT32){
            float* out = (float*)outv;
            if (resid) v += resid[off];
            out[off] = v;
            ps[j] += v; pq[j] += v*v;
          } else {
            u16* out = (u16*)outv;
            u16 q = f2h(v);
            out[off] = q;
            float vr = h2f(q);
            ps[j] += vr; pq[j] += vr*vr;
          }
        }
      }
    }
  }
  __syncthreads();
  if (tid < 128){ sumc[tid] = 0.f; sqc[tid] = 0.f; }
  __syncthreads();
  #pragma unroll
  for (int j = 0; j < 4; ++j){
    int cl = 64*wn + 16*j + ln;
    atomicAdd(&sumc[cl], ps[j]);
    atomicAdd(&sqc[cl],  pq[j]);
  }
  __syncthreads();
  if (tid < 128){
    atomicAdd(&sOut[cBase + tid], sumc[tid]);
    atomicAdd(&qOut[cBase + tid], sqc[tid]);
  }
}

// ---------------------------------------------------------------- pooling
__global__ __launch_bounds__(256) void k_pool(const float* __restrict__ h,
    const float* __restrict__ ssum, const float* __restrict__ ssq,
    const float* __restrict__ g, const float* __restrict__ b,
    const float* __restrict__ predW, const int* __restrict__ batch,
    float* __restrict__ pool, float* __restrict__ cnt, int N){
  int lane = threadIdx.x & 63;
  int n = (blockIdx.x << 2) + (threadIdx.x >> 6);
  if (n >= N) return;
  float inv = 1.f / (float)N;
  float v = 0.f;
  #pragma unroll
  for (int d = lane; d < 128; d += 64){
    float mu  = ssum[d]*inv;
    float var = fmaxf(ssq[d]*inv - mu*mu, 0.f);
    float rs  = rsqrtf(var + BNEPS);
    float bn  = (h[(size_t)n*128 + d] - mu)*(g[d]*rs) + b[d];
    v += bn * predW[d];
  }
  #pragma unroll
  for (int off = 32; off > 0; off >>= 1) v += __shfl_down(v, off, 64);
  if (lane == 0){
    int gi = batch[n];
    atomicAdd(&pool[gi], v);
    atomicAdd(&cnt[gi], 1.f);
  }
}

__global__ __launch_bounds__(256) void k_final(const float* __restrict__ pool,
    const float* __restrict__ cnt, const float* __restrict__ predb,
    float* __restrict__ out, int G){
  int g = blockIdx.x*256 + threadIdx.x;
  if (g < G) out[g] = pool[g] / fmaxf(cnt[g], 1.f) + predb[0];
}

// ---------------------------------------------------------------- launcher
extern "C" void kernel_launch(void* const* d_in, const int* in_sizes, int n_in,
                              void* d_out, int out_size, void* d_ws, size_t ws_size,
                              hipStream_t stream){
  const int*   x        = (const int*)d_in[0];
  const int*   eidx     = (const int*)d_in[1];
  const int*   eattr    = (const int*)d_in[2];
  const int*   batch    = (const int*)d_in[3];
  const float* atom_emb = (const float*)d_in[4];
  const float* bond_emb = (const float*)d_in[5];
  const float* W1 = (const float*)d_in[6];
  const float* b1 = (const float*)d_in[7];
  const float* g1 = (const float*)d_in[8];
  const float* be1= (const float*)d_in[9];
  const float* W2 = (const float*)d_in[10];
  const float* b2 = (const float*)d_in[11];
  const float* g2 = (const float*)d_in[12];
  const float* be2= (const float*)d_in[13];
  const float* W3 = (const float*)d_in[14];
  const float* b3 = (const float*)d_in[15];
  const float* tt = (const float*)d_in[16];
  const float* ng = (const float*)d_in[17];
  const float* nb = (const float*)d_in[18];
  const float* predW = (const float*)d_in[19];
  const float* predb = (const float*)d_in[20];
  float* out = (float*)d_out;

  const int N = in_sizes[3];
  const int E = in_sizes[1] / 2;
  const int L = in_sizes[16];
  const int G = out_size;
  const int D = 128, H = 256;
  const float invN = 1.f / (float)N;

  char* ws = (char*)d_ws;
  size_t off = 0;
  auto carve = [&](size_t bytes)->void*{
    void* p = ws + off;
    off += (bytes + 511) & ~(size_t)511;
    return p;
  };
  // total ~162 MB
  float* h   = (float*)carve((size_t)N*D*4);   // fp32 residual stream
  u16*   y1  = (u16*)  carve((size_t)N*H*2);   // fp16
  u16*   y2  = (u16*)  carve((size_t)N*H*2);   // fp16
  u16*   hh  = y2;   // hh (fp16, N*D) aliases y2; dead before GEMM2 writes y2
  u16*   Wt1 = (u16*) carve((size_t)L*H*D*2);  // [L][256][128]
  u16*   Wt2 = (u16*) carve((size_t)L*H*H*2);  // [L][256][256]
  u16*   Wt3 = (u16*) carve((size_t)L*D*H*2);  // [L][128][256]
  int*  offs   = (int*)carve((size_t)(N+1)*4);
  int*  cursor = (int*)carve((size_t)N*4);
  int*  cnt    = (int*)carve((size_t)N*4);
  int*  part   = (int*)carve(1024*4);
  int*  esort  = (int*)carve((size_t)E*4);
  float* stats = (float*)carve((size_t)L*1280*4);   // per-layer: s1(512) s2(512) sh(256)
  float* pool = (float*)carve((size_t)G*4);
  float* cntg = (float*)carve((size_t)G*4);

  int NB = (N + 255) / 256;

  // CSR build (once per call, shared by all 20 layers)
  k_zero_i   <<<NB, 256, 0, stream>>>(cnt, N);
  k_hist     <<<(E+255)/256, 256, 0, stream>>>(eidx + E, E, cnt);
  k_blocksum <<<NB, 256, 0, stream>>>(cnt, N, part);
  k_scanpart <<<1, 1024, 0, stream>>>(part, NB);
  k_scanapply<<<NB, 256, 0, stream>>>(cnt, part, N, E, offs, cursor);
  k_scatter  <<<(E+255)/256, 256, 0, stream>>>(eidx, eidx + E, eattr, E, cursor, esort);
  k_atom     <<<(N+1)/2, 256, 0, stream>>>(x, atom_emb, h, N);
  k_zero_f   <<<(L*1280+255)/256, 256, 0, stream>>>(stats, L*1280);

  // weights -> fp16 transposed [Nout][K]
  k_wtrans<<<((L*H*D)+255)/256, 256, 0, stream>>>(W1, Wt1, D, H, L*H*D);
  k_wtrans<<<((L*H*H)+255)/256, 256, 0, stream>>>(W2, Wt2, H, H, L*H*H);
  k_wtrans<<<((L*D*H)+255)/256, 256, 0, stream>>>(W3, Wt3, H, D, L*D*H);

  int mb = (N + 127) / 128;
  int eb = (N + 3) / 4;
  for (int l = 0; l < L; ++l){
    float* st  = stats + (size_t)l*1280;
    float* s1s = st,        *s1q = st + 256;
    float* s2s = st + 512,  *s2q = st + 768;
    float* shs = st + 1024, *shq = st + 1152;
    const float* bondl = bond_emb + (size_t)l*3*6*D;
    if (l == 0){
      k_edge<false><<<eb, 256, 0, stream>>>(h, offs, esort, bondl, tt + l,
          nullptr, nullptr, nullptr, nullptr, hh, N, invN);
    } else {
      float* stp = stats + (size_t)(l-1)*1280;
      k_edge<true><<<eb, 256, 0, stream>>>(h, offs, esort, bondl, tt + l,
          stp + 1024, stp + 1152, ng + (size_t)(l-1)*D, nb + (size_t)(l-1)*D,
          hh, N, invN);
    }
    // y1 = hh @ W1 + b1   (stats -> s1)
    k_gemm<false,false><<<dim3(mb,2), 256, 0, stream>>>(hh, D,
        Wt1 + (size_t)l*H*D, b1 + (size_t)l*H,
        nullptr, nullptr, nullptr, nullptr, nullptr,
        y1, H, s1s, s1q, N, D);
    // y2 = relu(bn(y1)) @ W2 + b2   (stats -> s2)
    k_gemm<true,false><<<dim3(mb,2), 256, 0, stream>>>(y1, H,
        Wt2 + (size_t)l*H*H, b2 + (size_t)l*H,
        s1s, s1q, g1 + (size_t)l*H, be1 + (size_t)l*H, nullptr,
        y2, H, s2s, s2q, N, H);
    // h = relu(bn(y2)) @ W3 + b3 (+ h residual for l>0)   (stats of new h -> sh)
    k_gemm<true,true><<<dim3(mb,1), 256, 0, stream>>>(y2, H,
        Wt3 + (size_t)l*D*H, b3 + (size_t)l*D,
        s2s, s2q, g2 + (size_t)l*H, be2 + (size_t)l*H,
        (l ? h : nullptr),
        h, D, shs, shq, N, H);
  }

  float* stL = stats + (size_t)(L-1)*1280;
  k_zero_f<<<(G+255)/256, 256, 0, stream>>>(pool, G);
  k_zero_f<<<(G+255)/256, 256, 0, stream>>>(cntg, G);
  k_pool  <<<(N+3)/4, 256, 0, stream>>>(h, stL + 1024, stL + 1152,
      ng + (size_t)(L-1)*D, nb + (size_t)(L-1)*D, predW, batch, pool, cntg, N);
  k_final <<<(G+255)/256, 256, 0, stream>>>(pool, cntg, predb, out, G);
}